// Round 9
// baseline (117.086 us; speedup 1.0000x reference)
//
#include <hip/hip_runtime.h>

// ChamferLoss: B=4, N=M=8192, D=3, fp32.
// loss = mean_b[ mean(pred2gt) + mean(gt2pred) + max(pred2gt) ]
// R9: 2-node graph. Harness analysis: dur_us always contains a fixed ~41us
// 268MB ws-poison fill + ~10us launch overhead; controllable budget in R8 was
// ~34us across 4 nodes. Changes:
//  - yprep also inits pmin (+inf) and the done counter -> no memset node.
//  - nn_mfma finishes with last-block final reduction (device-scope atomicAdd
//    + threadfence; agent-scope atomic loads are XCD-safe) -> no reduce node.
//  - hot loop: explicit next-iter B-frag prefetch; min3 folds ordered to keep
//    only 2 e-tiles live (~110 VGPR < 128 cap, 4 waves/SIMD).
// Math (verified R7/R8, absmax 0): bf16 hi/lo split,
//   A row m (K=16): [xh0..2, xh0..2, xl0..2, 1, 1, 0...]
//   B col n (K=16): [-2yh0..2, -2yl0..2, -2yh0..2, y2h, y2l, 0]
//   d2 = x2 + min_y (y2 - 2(xh.yh + xh.yl + xl.yh))   (xl.yl ~2^-18 dropped)

typedef short  s16x8  __attribute__((ext_vector_type(8)));
typedef float  f32x16 __attribute__((ext_vector_type(16)));

#define BATCH 4
#define NPTS  8192
#define TPB   256
#define YS    4                    // y slices per (b,dir)
#define YTILES (NPTS / 32)         // 256 y-tiles per (b,dir)
#define YTS   (YTILES / YS)        // 64 tiles per slice
#define XPB   256                  // x per block: 4 waves x 2 tiles x 32
#define NXC   (NPTS / XPB)         // 32
#define NBLK  (NXC * YS * 2 * BATCH)   // 1024

__device__ __forceinline__ unsigned int bft(float f) { return __float_as_uint(f) >> 16; }
__device__ __forceinline__ float bfv(unsigned int s) { return __uint_as_float(s << 16); }

// B-frags: bfrag[arr(2)][b(4)][tile(256)][half(2)][n(32)] x uint4.
// Also: pmin[gid] = +inf sentinel, done = 0.
__global__ __launch_bounds__(TPB)
void yprep(const float* __restrict__ pred, const float* __restrict__ gt,
           uint4* __restrict__ bfrag, unsigned int* __restrict__ pmin,
           unsigned int* __restrict__ done) {
    const int gid = blockIdx.x * TPB + threadIdx.x;    // 0..65535
    pmin[gid] = 0xFFFFFFFFu;
    if (gid == 0) *done = 0u;
    const int arr = gid >> 15;                         // 0=pred, 1=gt
    const int rem = gid & 32767;                       // b*NPTS + yi
    const int yi  = rem & (NPTS - 1);
    const float* y = (arr ? gt : pred) + (size_t)rem * 3;
    const float a0 = y[0], a1 = y[1], a2 = y[2];
    const unsigned int yh0 = bft(a0), yh1 = bft(a1), yh2 = bft(a2);
    const float l0 = a0 - bfv(yh0), l1 = a1 - bfv(yh1), l2 = a2 - bfv(yh2);
    const unsigned int nh0 = bft(-2.f * bfv(yh0));     // exact in bf16
    const unsigned int nh1 = bft(-2.f * bfv(yh1));
    const unsigned int nh2 = bft(-2.f * bfv(yh2));
    const unsigned int nl0 = bft(-2.f * l0), nl1 = bft(-2.f * l1), nl2 = bft(-2.f * l2);
    const float y2 = a0 * a0 + a1 * a1 + a2 * a2;
    const unsigned int q2h = bft(y2);
    const unsigned int q2l = bft(y2 - bfv(q2h));
    uint4 w0, w1;                                      // k-order halves
    w0.x = nh0 | (nh1 << 16);
    w0.y = nh2 | (nl0 << 16);
    w0.z = nl1 | (nl2 << 16);
    w0.w = nh0 | (nh1 << 16);
    w1.x = nh2 | (q2h << 16);
    w1.y = q2l;
    w1.z = 0u; w1.w = 0u;
    const size_t base = ((size_t)(gid >> 13) * YTILES + (yi >> 5)) * 64;  // (arr*4+b)
    bfrag[base + (yi & 31)]      = w0;
    bfrag[base + 32 + (yi & 31)] = w1;
}

__global__ __launch_bounds__(TPB, 4)
void nn_mfma(const float* __restrict__ pred, const float* __restrict__ gt,
             const uint4* __restrict__ bfrag, unsigned int* __restrict__ pmin,
             unsigned int* __restrict__ done, float* __restrict__ out) {
    const int xc = blockIdx.x, sl = blockIdx.y, bd = blockIdx.z;
    const int b = bd >> 1, dir = bd & 1;
    const float* xp = (dir ? gt : pred) + (size_t)b * NPTS * 3;
    const int yarr = dir ? 0 : 1;                      // y = dir ? pred : gt
    const uint4* bfb = bfrag + (size_t)(yarr * BATCH + b) * YTILES * 64;

    const int t = threadIdx.x;
    const int w = t >> 6, l = t & 63;
    const int m32 = l & 31, hh = l >> 5;
    const int xbase = xc * XPB + w * 64;

    // A-frags + x2 for the wave's two 32-row x-tiles.
    s16x8 af[2];
    float x2j[2];
    #pragma unroll
    for (int j = 0; j < 2; ++j) {
        const int xi = xbase + j * 32 + m32;
        const float c0 = xp[xi * 3], c1 = xp[xi * 3 + 1], c2 = xp[xi * 3 + 2];
        x2j[j] = c0 * c0 + c1 * c1 + c2 * c2;
        const unsigned int xh0 = bft(c0), xh1 = bft(c1), xh2 = bft(c2);
        const unsigned int xl0 = bft(c0 - bfv(xh0));
        const unsigned int xl1 = bft(c1 - bfv(xh1));
        const unsigned int xl2 = bft(c2 - bfv(xh2));
        s16x8 a;                                       // k = hh*8 + e
        a[0] = (short)(hh ? xl2 : xh0);
        a[1] = (short)(hh ? 0x3F80u : xh1);            // 1.0 bf16 (y2h)
        a[2] = (short)(hh ? 0x3F80u : xh2);            // 1.0 bf16 (y2l)
        a[3] = (short)(hh ? 0u : xh0);
        a[4] = (short)(hh ? 0u : xh1);
        a[5] = (short)(hh ? 0u : xh2);
        a[6] = (short)(hh ? 0u : xl0);
        a[7] = (short)(hh ? 0u : xl1);
        af[j] = a;
    }

    f32x16 zero, mn0, mn1;
    #pragma unroll
    for (int r = 0; r < 16; ++r) { zero[r] = 0.f; mn0[r] = 3.4e38f; mn1[r] = 3.4e38f; }

    // Hot loop with explicit next-iter prefetch: per iter 2 coalesced 1KB
    // loads + 4 MFMA (matrix pipe) + 32 v_min3 (64 VALU cy per 4096 pairs).
    const uint4* bp = bfb + (size_t)(sl * YTS) * 64 + l;
    uint4 c0 = bp[0], c1 = bp[64]; bp += 128;
    for (int it = 0; it < YTS / 2 - 1; ++it) {
        const uint4 n0 = bp[0], n1 = bp[64]; bp += 128;
        const s16x8 bf0 = __builtin_bit_cast(s16x8, c0);
        const s16x8 bf1 = __builtin_bit_cast(s16x8, c1);
        const f32x16 e00 = __builtin_amdgcn_mfma_f32_32x32x16_bf16(af[0], bf0, zero, 0, 0, 0);
        const f32x16 e01 = __builtin_amdgcn_mfma_f32_32x32x16_bf16(af[0], bf1, zero, 0, 0, 0);
        mn0 = __builtin_elementwise_min(mn0, __builtin_elementwise_min(e00, e01));
        const f32x16 e10 = __builtin_amdgcn_mfma_f32_32x32x16_bf16(af[1], bf0, zero, 0, 0, 0);
        const f32x16 e11 = __builtin_amdgcn_mfma_f32_32x32x16_bf16(af[1], bf1, zero, 0, 0, 0);
        mn1 = __builtin_elementwise_min(mn1, __builtin_elementwise_min(e10, e11));
        c0 = n0; c1 = n1;
    }
    {   // tail iteration
        const s16x8 bf0 = __builtin_bit_cast(s16x8, c0);
        const s16x8 bf1 = __builtin_bit_cast(s16x8, c1);
        const f32x16 e00 = __builtin_amdgcn_mfma_f32_32x32x16_bf16(af[0], bf0, zero, 0, 0, 0);
        const f32x16 e01 = __builtin_amdgcn_mfma_f32_32x32x16_bf16(af[0], bf1, zero, 0, 0, 0);
        mn0 = __builtin_elementwise_min(mn0, __builtin_elementwise_min(e00, e01));
        const f32x16 e10 = __builtin_amdgcn_mfma_f32_32x32x16_bf16(af[1], bf0, zero, 0, 0, 0);
        const f32x16 e11 = __builtin_amdgcn_mfma_f32_32x32x16_bf16(af[1], bf1, zero, 0, 0, 0);
        mn1 = __builtin_elementwise_min(mn1, __builtin_elementwise_min(e10, e11));
    }

    // Butterfly min across the 32 cols (stays within each 32-lane half).
    #pragma unroll
    for (int off = 16; off; off >>= 1) {
        #pragma unroll
        for (int r = 0; r < 16; ++r) {
            mn0[r] = fminf(mn0[r], __shfl_xor(mn0[r], off, 64));
            mn1[r] = fminf(mn1[r], __shfl_xor(mn1[r], off, 64));
        }
    }

    // Lane l owns r = l&15; (l&31)>=16 -> tile1. One atomicMin per lane.
    const int r = l & 15;
    const int row = (r & 3) + 8 * (r >> 2) + 4 * hh;   // C/D row map (m74/m101)
    float v0 = mn0[0], v1 = mn1[0];
    #pragma unroll
    for (int rr = 1; rr < 16; ++rr) {
        v0 = (r == rr) ? mn0[rr] : v0;
        v1 = (r == rr) ? mn1[rr] : v1;
    }
    const float x20 = __shfl(x2j[0], row, 64);
    const float x21 = __shfl(x2j[1], row, 64);
    const bool g1 = (l & 31) >= 16;
    const float d = fmaxf((g1 ? v1 : v0) + (g1 ? x21 : x20), 0.f);
    const int xpt = xbase + (g1 ? 32 : 0) + row;
    atomicMin(&pmin[(size_t)bd * NPTS + xpt], __float_as_uint(d));

    // ---- last-block final reduction (device-scope handoff) ----
    __shared__ int lastflag;
    __syncthreads();
    if (t == 0) {
        __threadfence();                               // mins visible before count
        const unsigned int old = atomicAdd(done, 1u);
        lastflag = (old == NBLK - 1);
        __threadfence();
    }
    __syncthreads();
    if (!lastflag) return;

    // 32 threads per bd-group; agent-scope atomic loads (XCD-coherence-safe).
    const int gbd = t >> 5, l32 = t & 31;
    const unsigned int* base = pmin + (size_t)gbd * NPTS;
    float sum = 0.f, mx = -1.f;
    for (int i = 0; i < NPTS / 32; ++i) {
        const unsigned int u = __hip_atomic_load(&base[i * 32 + l32],
                                                 __ATOMIC_RELAXED,
                                                 __HIP_MEMORY_SCOPE_AGENT);
        const float f = __uint_as_float(u);
        sum += f;
        mx = fmaxf(mx, f);
    }
    #pragma unroll
    for (int off = 16; off; off >>= 1) {
        sum += __shfl_down(sum, off, 32);
        mx = fmaxf(mx, __shfl_down(mx, off, 32));
    }
    __shared__ float ss[8], sm[8];
    if (l32 == 0) { ss[gbd] = sum; sm[gbd] = mx; }
    __syncthreads();
    if (t == 0) {
        float acc = 0.f;
        #pragma unroll
        for (int d2 = 0; d2 < 8; d2 += 2)   // even: pred2gt (mean+max), odd: gt2pred (mean)
            acc += ss[d2] * (1.f / NPTS) + ss[d2 + 1] * (1.f / NPTS) + sm[d2];
        out[0] = acc * (1.f / BATCH);
    }
}

extern "C" void kernel_launch(void* const* d_in, const int* in_sizes, int n_in,
                              void* d_out, int out_size, void* d_ws, size_t ws_size,
                              hipStream_t stream) {
    const float* pred = (const float*)d_in[0];
    const float* gt   = (const float*)d_in[1];

    unsigned int* pmin = (unsigned int*)d_ws;                               // 256 KB
    uint4* bfrag = (uint4*)((char*)d_ws + (size_t)2 * BATCH * NPTS * 4);    // 2 MB
    unsigned int* done = (unsigned int*)((char*)d_ws + (size_t)2 * BATCH * NPTS * 4
                                         + (size_t)2 * BATCH * YTILES * 64 * 16);

    yprep<<<dim3(2 * BATCH * NPTS / TPB), TPB, 0, stream>>>(pred, gt, bfrag, pmin, done);
    dim3 g1(NXC, YS, 2 * BATCH);   // 32 x 4 x 8 = 1024 blocks (4/CU)
    nn_mfma<<<g1, TPB, 0, stream>>>(pred, gt, bfrag, pmin, done, (float*)d_out);
}

// Round 10
// 108.616 us; speedup vs baseline: 1.0780x; 1.0780x over previous
//
#include <hip/hip_runtime.h>

// ChamferLoss: B=4, N=M=8192, D=3, fp32.
// loss = mean_b[ mean(pred2gt) + mean(gt2pred) + max(pred2gt) ]
// R10: R9's manual prefetch was a zero-distance pipeline (vmcnt(0) every iter
// -> 64.5us, both pipes <17%). Fix: LDS-stage the block's 64KB y-slice in two
// 32KB phases via global_load_lds width=16 (tile layout is exactly the
// wave-uniform-base + lane*16 pattern; 1 tile = 1KB = 1 instr/wave). Steady
// state reads ds_read_b128 (~12cy) under a 64cy VALU body -> latency paid
// twice per block, not per iter. Keep 2-node graph + verified math/epilogue.
//   A row m (K=16): [xh0..2, xh0..2, xl0..2, 1, 1, 0...]
//   B col n (K=16): [-2yh0..2, -2yl0..2, -2yh0..2, y2h, y2l, 0]
//   d2 = x2 + min_y (y2 - 2(xh.yh + xh.yl + xl.yh))   (xl.yl ~2^-18 dropped)

typedef short  s16x8  __attribute__((ext_vector_type(8)));
typedef float  f32x16 __attribute__((ext_vector_type(16)));

#define BATCH 4
#define NPTS  8192
#define TPB   256
#define YS    4                    // y slices per (b,dir)
#define YTILES (NPTS / 32)         // 256 y-tiles per (b,dir)
#define YTS   (YTILES / YS)        // 64 tiles per slice
#define PHT   32                   // tiles per staging phase (32 KB)
#define XPB   256                  // x per block: 4 waves x 2 tiles x 32
#define NXC   (NPTS / XPB)         // 32
#define NBLK  (NXC * YS * 2 * BATCH)   // 1024

__device__ __forceinline__ unsigned int bft(float f) { return __float_as_uint(f) >> 16; }
__device__ __forceinline__ float bfv(unsigned int s) { return __uint_as_float(s << 16); }

__device__ __forceinline__ void gl_lds16(const uint4* g, uint4* s) {
    __builtin_amdgcn_global_load_lds(
        (const __attribute__((address_space(1))) void*)g,
        (__attribute__((address_space(3))) void*)s, 16, 0, 0);
}

// B-frags: bfrag[arr(2)][b(4)][tile(256)][half(2)][n(32)] x uint4.
// Also: pmin[gid] = +inf sentinel, done = 0.
__global__ __launch_bounds__(TPB)
void yprep(const float* __restrict__ pred, const float* __restrict__ gt,
           uint4* __restrict__ bfrag, unsigned int* __restrict__ pmin,
           unsigned int* __restrict__ done) {
    const int gid = blockIdx.x * TPB + threadIdx.x;    // 0..65535
    pmin[gid] = 0xFFFFFFFFu;
    if (gid == 0) *done = 0u;
    const int arr = gid >> 15;                         // 0=pred, 1=gt
    const int rem = gid & 32767;                       // b*NPTS + yi
    const int yi  = rem & (NPTS - 1);
    const float* y = (arr ? gt : pred) + (size_t)rem * 3;
    const float a0 = y[0], a1 = y[1], a2 = y[2];
    const unsigned int yh0 = bft(a0), yh1 = bft(a1), yh2 = bft(a2);
    const float l0 = a0 - bfv(yh0), l1 = a1 - bfv(yh1), l2 = a2 - bfv(yh2);
    const unsigned int nh0 = bft(-2.f * bfv(yh0));     // exact in bf16
    const unsigned int nh1 = bft(-2.f * bfv(yh1));
    const unsigned int nh2 = bft(-2.f * bfv(yh2));
    const unsigned int nl0 = bft(-2.f * l0), nl1 = bft(-2.f * l1), nl2 = bft(-2.f * l2);
    const float y2 = a0 * a0 + a1 * a1 + a2 * a2;
    const unsigned int q2h = bft(y2);
    const unsigned int q2l = bft(y2 - bfv(q2h));
    uint4 w0, w1;                                      // k-order halves
    w0.x = nh0 | (nh1 << 16);
    w0.y = nh2 | (nl0 << 16);
    w0.z = nl1 | (nl2 << 16);
    w0.w = nh0 | (nh1 << 16);
    w1.x = nh2 | (q2h << 16);
    w1.y = q2l;
    w1.z = 0u; w1.w = 0u;
    const size_t base = ((size_t)(gid >> 13) * YTILES + (yi >> 5)) * 64;  // (arr*4+b)
    bfrag[base + (yi & 31)]      = w0;
    bfrag[base + 32 + (yi & 31)] = w1;
}

__global__ __launch_bounds__(TPB, 4)
void nn_mfma(const float* __restrict__ pred, const float* __restrict__ gt,
             const uint4* __restrict__ bfrag, unsigned int* __restrict__ pmin,
             unsigned int* __restrict__ done, float* __restrict__ out) {
    const int xc = blockIdx.x, sl = blockIdx.y, bd = blockIdx.z;
    const int b = bd >> 1, dir = bd & 1;
    const float* xp = (dir ? gt : pred) + (size_t)b * NPTS * 3;
    const int yarr = dir ? 0 : 1;                      // y = dir ? pred : gt
    const uint4* bfb = bfrag + (size_t)(yarr * BATCH + b) * YTILES * 64
                       + (size_t)(sl * YTS) * 64;

    __shared__ uint4 ystage[PHT * 64];                 // 32 KB, one phase
    __shared__ float ss[8], sm[8];
    __shared__ int lastflag;

    const int t = threadIdx.x;
    const int w = t >> 6, l = t & 63;
    const int m32 = l & 31, hh = l >> 5;
    const int xbase = xc * XPB + w * 64;

    // A-frags + x2 for the wave's two 32-row x-tiles.
    s16x8 af[2];
    float x2j[2];
    #pragma unroll
    for (int j = 0; j < 2; ++j) {
        const int xi = xbase + j * 32 + m32;
        const float c0 = xp[xi * 3], c1 = xp[xi * 3 + 1], c2 = xp[xi * 3 + 2];
        x2j[j] = c0 * c0 + c1 * c1 + c2 * c2;
        const unsigned int xh0 = bft(c0), xh1 = bft(c1), xh2 = bft(c2);
        const unsigned int xl0 = bft(c0 - bfv(xh0));
        const unsigned int xl1 = bft(c1 - bfv(xh1));
        const unsigned int xl2 = bft(c2 - bfv(xh2));
        s16x8 a;                                       // k = hh*8 + e
        a[0] = (short)(hh ? xl2 : xh0);
        a[1] = (short)(hh ? 0x3F80u : xh1);            // 1.0 bf16 (y2h)
        a[2] = (short)(hh ? 0x3F80u : xh2);            // 1.0 bf16 (y2l)
        a[3] = (short)(hh ? 0u : xh0);
        a[4] = (short)(hh ? 0u : xh1);
        a[5] = (short)(hh ? 0u : xh2);
        a[6] = (short)(hh ? 0u : xl0);
        a[7] = (short)(hh ? 0u : xl1);
        af[j] = a;
    }

    f32x16 zero, mn0, mn1;
    #pragma unroll
    for (int r = 0; r < 16; ++r) { zero[r] = 0.f; mn0[r] = 3.4e38f; mn1[r] = 3.4e38f; }

    const s16x8* sy = (const s16x8*)ystage;
    for (int ph = 0; ph < YTS / PHT; ++ph) {
        // Stage PHT tiles: wave w loads tiles w*8+i (1 KB each, lane-contig).
        #pragma unroll
        for (int i = 0; i < PHT / 4; ++i) {
            const int tt = w * (PHT / 4) + i;
            gl_lds16(bfb + (size_t)(ph * PHT + tt) * 64 + l, ystage + tt * 64);
        }
        __syncthreads();   // drains vmcnt for global_load_lds

        #pragma unroll 4
        for (int tt = 0; tt < PHT; tt += 2) {
            const s16x8 bf0 = sy[tt * 64 + l];
            const s16x8 bf1 = sy[(tt + 1) * 64 + l];
            const f32x16 e00 = __builtin_amdgcn_mfma_f32_32x32x16_bf16(af[0], bf0, zero, 0, 0, 0);
            const f32x16 e01 = __builtin_amdgcn_mfma_f32_32x32x16_bf16(af[0], bf1, zero, 0, 0, 0);
            mn0 = __builtin_elementwise_min(mn0, __builtin_elementwise_min(e00, e01));
            const f32x16 e10 = __builtin_amdgcn_mfma_f32_32x32x16_bf16(af[1], bf0, zero, 0, 0, 0);
            const f32x16 e11 = __builtin_amdgcn_mfma_f32_32x32x16_bf16(af[1], bf1, zero, 0, 0, 0);
            mn1 = __builtin_elementwise_min(mn1, __builtin_elementwise_min(e10, e11));
        }
        __syncthreads();   // before next phase overwrites ystage
    }

    // Butterfly min across the 32 cols (stays within each 32-lane half).
    #pragma unroll
    for (int off = 16; off; off >>= 1) {
        #pragma unroll
        for (int r = 0; r < 16; ++r) {
            mn0[r] = fminf(mn0[r], __shfl_xor(mn0[r], off, 64));
            mn1[r] = fminf(mn1[r], __shfl_xor(mn1[r], off, 64));
        }
    }

    // Lane l owns r = l&15; (l&31)>=16 -> tile1. One atomicMin per lane.
    const int r = l & 15;
    const int row = (r & 3) + 8 * (r >> 2) + 4 * hh;   // C/D row map (m74/m101)
    float v0 = mn0[0], v1 = mn1[0];
    #pragma unroll
    for (int rr = 1; rr < 16; ++rr) {
        v0 = (r == rr) ? mn0[rr] : v0;
        v1 = (r == rr) ? mn1[rr] : v1;
    }
    const float x20 = __shfl(x2j[0], row, 64);
    const float x21 = __shfl(x2j[1], row, 64);
    const bool g1 = (l & 31) >= 16;
    const float d = fmaxf((g1 ? v1 : v0) + (g1 ? x21 : x20), 0.f);
    const int xpt = xbase + (g1 ? 32 : 0) + row;
    atomicMin(&pmin[(size_t)bd * NPTS + xpt], __float_as_uint(d));

    // ---- last-block final reduction (device-scope handoff) ----
    __syncthreads();
    if (t == 0) {
        __threadfence();                               // mins visible before count
        const unsigned int old = atomicAdd(done, 1u);
        lastflag = (old == NBLK - 1);
    }
    __syncthreads();
    if (!lastflag) return;

    // 32 threads per bd-group; agent-scope atomic loads (XCD-coherence-safe).
    const int gbd = t >> 5, l32 = t & 31;
    const unsigned int* base = pmin + (size_t)gbd * NPTS;
    float sum = 0.f, mx = -1.f;
    for (int i = 0; i < NPTS / 32; ++i) {
        const unsigned int u = __hip_atomic_load(&base[i * 32 + l32],
                                                 __ATOMIC_RELAXED,
                                                 __HIP_MEMORY_SCOPE_AGENT);
        const float f = __uint_as_float(u);
        sum += f;
        mx = fmaxf(mx, f);
    }
    #pragma unroll
    for (int off = 16; off; off >>= 1) {
        sum += __shfl_down(sum, off, 32);
        mx = fmaxf(mx, __shfl_down(mx, off, 32));
    }
    if (l32 == 0) { ss[gbd] = sum; sm[gbd] = mx; }
    __syncthreads();
    if (t == 0) {
        float acc = 0.f;
        #pragma unroll
        for (int d2 = 0; d2 < 8; d2 += 2)   // even: pred2gt (mean+max), odd: gt2pred (mean)
            acc += ss[d2] * (1.f / NPTS) + ss[d2 + 1] * (1.f / NPTS) + sm[d2];
        out[0] = acc * (1.f / BATCH);
    }
}

extern "C" void kernel_launch(void* const* d_in, const int* in_sizes, int n_in,
                              void* d_out, int out_size, void* d_ws, size_t ws_size,
                              hipStream_t stream) {
    const float* pred = (const float*)d_in[0];
    const float* gt   = (const float*)d_in[1];

    unsigned int* pmin = (unsigned int*)d_ws;                               // 256 KB
    uint4* bfrag = (uint4*)((char*)d_ws + (size_t)2 * BATCH * NPTS * 4);    // 2 MB
    unsigned int* done = (unsigned int*)((char*)d_ws + (size_t)2 * BATCH * NPTS * 4
                                         + (size_t)2 * BATCH * YTILES * 64 * 16);

    yprep<<<dim3(2 * BATCH * NPTS / TPB), TPB, 0, stream>>>(pred, gt, bfrag, pmin, done);
    dim3 g1(NXC, YS, 2 * BATCH);   // 32 x 4 x 8 = 1024 blocks (4/CU)
    nn_mfma<<<g1, TPB, 0, stream>>>(pred, gt, bfrag, pmin, done, (float*)d_out);
}

// Round 11
// 100.613 us; speedup vs baseline: 1.1637x; 1.0795x over previous
//
#include <hip/hip_runtime.h>

// ChamferLoss: B=4, N=M=8192, D=3, fp32.
// loss = mean_b[ mean(pred2gt) + mean(gt2pred) + max(pred2gt) ]
// R11: R9/R10's ~65us was the fused last-block tail (256 serial agent-scope
// atomic loads/lane by ONE block ~50us), not the body. Revert to a separate
// reduce kernel (R8's, plain loads, ~4us, correctness-proven) and keep:
//  - yprep inits pmin (+inf) -> no memset node (3 nodes total).
//  - nn_mfma: R10's LDS-staged MFMA body (global_load_lds width=16, two
//    32KB phases, ds_read_b128 conflict-free), atomicMin epilogue.
// Math (absmax 0 since R7): bf16 hi/lo split,
//   A row m (K=16): [xh0..2, xh0..2, xl0..2, 1, 1, 0...]
//   B col n (K=16): [-2yh0..2, -2yl0..2, -2yh0..2, y2h, y2l, 0]
//   d2 = x2 + min_y (y2 - 2(xh.yh + xh.yl + xl.yh))   (xl.yl ~2^-18 dropped)

typedef short  s16x8  __attribute__((ext_vector_type(8)));
typedef float  f32x16 __attribute__((ext_vector_type(16)));

#define BATCH 4
#define NPTS  8192
#define TPB   256
#define YS    4                    // y slices per (b,dir)
#define YTILES (NPTS / 32)         // 256 y-tiles per (b,dir)
#define YTS   (YTILES / YS)        // 64 tiles per slice
#define PHT   32                   // tiles per staging phase (32 KB)
#define XPB   256                  // x per block: 4 waves x 2 tiles x 32
#define NXC   (NPTS / XPB)         // 32

__device__ __forceinline__ unsigned int bft(float f) { return __float_as_uint(f) >> 16; }
__device__ __forceinline__ float bfv(unsigned int s) { return __uint_as_float(s << 16); }

__device__ __forceinline__ void gl_lds16(const uint4* g, uint4* s) {
    __builtin_amdgcn_global_load_lds(
        (const __attribute__((address_space(1))) void*)g,
        (__attribute__((address_space(3))) void*)s, 16, 0, 0);
}

// B-frags: bfrag[arr(2)][b(4)][tile(256)][half(2)][n(32)] x uint4.
// Also: pmin[gid] = +inf sentinel.
__global__ __launch_bounds__(TPB)
void yprep(const float* __restrict__ pred, const float* __restrict__ gt,
           uint4* __restrict__ bfrag, unsigned int* __restrict__ pmin) {
    const int gid = blockIdx.x * TPB + threadIdx.x;    // 0..65535
    pmin[gid] = 0xFFFFFFFFu;
    const int arr = gid >> 15;                         // 0=pred, 1=gt
    const int rem = gid & 32767;                       // b*NPTS + yi
    const int yi  = rem & (NPTS - 1);
    const float* y = (arr ? gt : pred) + (size_t)rem * 3;
    const float a0 = y[0], a1 = y[1], a2 = y[2];
    const unsigned int yh0 = bft(a0), yh1 = bft(a1), yh2 = bft(a2);
    const float l0 = a0 - bfv(yh0), l1 = a1 - bfv(yh1), l2 = a2 - bfv(yh2);
    const unsigned int nh0 = bft(-2.f * bfv(yh0));     // exact in bf16
    const unsigned int nh1 = bft(-2.f * bfv(yh1));
    const unsigned int nh2 = bft(-2.f * bfv(yh2));
    const unsigned int nl0 = bft(-2.f * l0), nl1 = bft(-2.f * l1), nl2 = bft(-2.f * l2);
    const float y2 = a0 * a0 + a1 * a1 + a2 * a2;
    const unsigned int q2h = bft(y2);
    const unsigned int q2l = bft(y2 - bfv(q2h));
    uint4 w0, w1;                                      // k-order halves
    w0.x = nh0 | (nh1 << 16);
    w0.y = nh2 | (nl0 << 16);
    w0.z = nl1 | (nl2 << 16);
    w0.w = nh0 | (nh1 << 16);
    w1.x = nh2 | (q2h << 16);
    w1.y = q2l;
    w1.z = 0u; w1.w = 0u;
    const size_t base = ((size_t)(gid >> 13) * YTILES + (yi >> 5)) * 64;  // (arr*4+b)
    bfrag[base + (yi & 31)]      = w0;
    bfrag[base + 32 + (yi & 31)] = w1;
}

__global__ __launch_bounds__(TPB, 4)
void nn_mfma(const float* __restrict__ pred, const float* __restrict__ gt,
             const uint4* __restrict__ bfrag, unsigned int* __restrict__ pmin) {
    const int xc = blockIdx.x, sl = blockIdx.y, bd = blockIdx.z;
    const int b = bd >> 1, dir = bd & 1;
    const float* xp = (dir ? gt : pred) + (size_t)b * NPTS * 3;
    const int yarr = dir ? 0 : 1;                      // y = dir ? pred : gt
    const uint4* bfb = bfrag + (size_t)(yarr * BATCH + b) * YTILES * 64
                       + (size_t)(sl * YTS) * 64;

    __shared__ uint4 ystage[PHT * 64];                 // 32 KB, one phase

    const int t = threadIdx.x;
    const int w = t >> 6, l = t & 63;
    const int m32 = l & 31, hh = l >> 5;
    const int xbase = xc * XPB + w * 64;

    // A-frags + x2 for the wave's two 32-row x-tiles.
    s16x8 af[2];
    float x2j[2];
    #pragma unroll
    for (int j = 0; j < 2; ++j) {
        const int xi = xbase + j * 32 + m32;
        const float c0 = xp[xi * 3], c1 = xp[xi * 3 + 1], c2 = xp[xi * 3 + 2];
        x2j[j] = c0 * c0 + c1 * c1 + c2 * c2;
        const unsigned int xh0 = bft(c0), xh1 = bft(c1), xh2 = bft(c2);
        const unsigned int xl0 = bft(c0 - bfv(xh0));
        const unsigned int xl1 = bft(c1 - bfv(xh1));
        const unsigned int xl2 = bft(c2 - bfv(xh2));
        s16x8 a;                                       // k = hh*8 + e
        a[0] = (short)(hh ? xl2 : xh0);
        a[1] = (short)(hh ? 0x3F80u : xh1);            // 1.0 bf16 (y2h)
        a[2] = (short)(hh ? 0x3F80u : xh2);            // 1.0 bf16 (y2l)
        a[3] = (short)(hh ? 0u : xh0);
        a[4] = (short)(hh ? 0u : xh1);
        a[5] = (short)(hh ? 0u : xh2);
        a[6] = (short)(hh ? 0u : xl0);
        a[7] = (short)(hh ? 0u : xl1);
        af[j] = a;
    }

    f32x16 zero, mn0, mn1;
    #pragma unroll
    for (int r = 0; r < 16; ++r) { zero[r] = 0.f; mn0[r] = 3.4e38f; mn1[r] = 3.4e38f; }

    const s16x8* sy = (const s16x8*)ystage;
    for (int ph = 0; ph < YTS / PHT; ++ph) {
        // Stage PHT tiles: wave w loads tiles w*8+i (1 KB each, lane-contig).
        #pragma unroll
        for (int i = 0; i < PHT / 4; ++i) {
            const int tt = w * (PHT / 4) + i;
            gl_lds16(bfb + (size_t)(ph * PHT + tt) * 64 + l, ystage + tt * 64);
        }
        __syncthreads();   // drains vmcnt for global_load_lds

        #pragma unroll 4
        for (int tt = 0; tt < PHT; tt += 2) {
            const s16x8 bf0 = sy[tt * 64 + l];
            const s16x8 bf1 = sy[(tt + 1) * 64 + l];
            const f32x16 e00 = __builtin_amdgcn_mfma_f32_32x32x16_bf16(af[0], bf0, zero, 0, 0, 0);
            const f32x16 e01 = __builtin_amdgcn_mfma_f32_32x32x16_bf16(af[0], bf1, zero, 0, 0, 0);
            mn0 = __builtin_elementwise_min(mn0, __builtin_elementwise_min(e00, e01));
            const f32x16 e10 = __builtin_amdgcn_mfma_f32_32x32x16_bf16(af[1], bf0, zero, 0, 0, 0);
            const f32x16 e11 = __builtin_amdgcn_mfma_f32_32x32x16_bf16(af[1], bf1, zero, 0, 0, 0);
            mn1 = __builtin_elementwise_min(mn1, __builtin_elementwise_min(e10, e11));
        }
        __syncthreads();   // before next phase overwrites ystage
    }

    // Butterfly min across the 32 cols (stays within each 32-lane half).
    #pragma unroll
    for (int off = 16; off; off >>= 1) {
        #pragma unroll
        for (int r = 0; r < 16; ++r) {
            mn0[r] = fminf(mn0[r], __shfl_xor(mn0[r], off, 64));
            mn1[r] = fminf(mn1[r], __shfl_xor(mn1[r], off, 64));
        }
    }

    // Lane l owns r = l&15; (l&31)>=16 -> tile1. One atomicMin per lane.
    const int r = l & 15;
    const int row = (r & 3) + 8 * (r >> 2) + 4 * hh;   // C/D row map (m74/m101)
    float v0 = mn0[0], v1 = mn1[0];
    #pragma unroll
    for (int rr = 1; rr < 16; ++rr) {
        v0 = (r == rr) ? mn0[rr] : v0;
        v1 = (r == rr) ? mn1[rr] : v1;
    }
    const float x20 = __shfl(x2j[0], row, 64);
    const float x21 = __shfl(x2j[1], row, 64);
    const bool g1 = (l & 31) >= 16;
    const float d = fmaxf((g1 ? v1 : v0) + (g1 ? x21 : x20), 0.f);
    const int xpt = xbase + (g1 ? 32 : 0) + row;
    atomicMin(&pmin[(size_t)bd * NPTS + xpt], __float_as_uint(d));
}

// One 1024-thread block: 128 threads per bd; sum + max per bd; write out[0].
// Plain cacheable loads: kernel boundary orders them after nn_mfma's atomics
// (correctness proven in R8, absmax 0).
__global__ __launch_bounds__(1024)
void reduce_all(const unsigned int* __restrict__ pmin, float* __restrict__ out) {
    const int t  = threadIdx.x;
    const int bd = t >> 7;
    const int l  = t & 127;
    const unsigned int* base = pmin + (size_t)bd * NPTS;
    float sum = 0.f, mx = -1.f;
    #pragma unroll
    for (int i = 0; i < NPTS / 128; ++i) {
        const float f = __uint_as_float(base[i * 128 + l]);
        sum += f;
        mx = fmaxf(mx, f);
    }
    #pragma unroll
    for (int off = 32; off; off >>= 1) {
        sum += __shfl_down(sum, off, 64);
        mx = fmaxf(mx, __shfl_down(mx, off, 64));
    }
    __shared__ float ss[16], sm[16];
    if ((t & 63) == 0) { ss[t >> 6] = sum; sm[t >> 6] = mx; }
    __syncthreads();
    if (t == 0) {
        float acc = 0.f;
        #pragma unroll
        for (int d = 0; d < 8; ++d) {
            const float S = ss[2 * d] + ss[2 * d + 1];
            const float M = fmaxf(sm[2 * d], sm[2 * d + 1]);
            acc += S * (1.f / NPTS) + ((d & 1) ? 0.f : M);   // max only for pred2gt
        }
        out[0] = acc * (1.f / BATCH);
    }
}

extern "C" void kernel_launch(void* const* d_in, const int* in_sizes, int n_in,
                              void* d_out, int out_size, void* d_ws, size_t ws_size,
                              hipStream_t stream) {
    const float* pred = (const float*)d_in[0];
    const float* gt   = (const float*)d_in[1];

    unsigned int* pmin = (unsigned int*)d_ws;                               // 256 KB
    uint4* bfrag = (uint4*)((char*)d_ws + (size_t)2 * BATCH * NPTS * 4);    // 2 MB

    yprep<<<dim3(2 * BATCH * NPTS / TPB), TPB, 0, stream>>>(pred, gt, bfrag, pmin);
    dim3 g1(NXC, YS, 2 * BATCH);   // 32 x 4 x 8 = 1024 blocks (4/CU)
    nn_mfma<<<g1, TPB, 0, stream>>>(pred, gt, bfrag, pmin);
    reduce_all<<<dim3(1), 1024, 0, stream>>>(pmin, (float*)d_out);
}

// Round 12
// 99.269 us; speedup vs baseline: 1.1795x; 1.0135x over previous
//
#include <hip/hip_runtime.h>

// ChamferLoss: B=4, N=M=8192, D=3, fp32.
// loss = mean_b[ mean(pred2gt) + mean(gt2pred) + max(pred2gt) ]
// R12: back to R8's compiler-scheduled global-load body (best measured body,
// ~25us vs R11's LDS-staged 45us). Fix the VALU excess: R11 reported VGPR=64
// under a 128 cap -> e-tiles in AGPRs (unified file, count hidden) -> ~16
// v_accvgpr moves per MFMA + serialized MFMA->min chains. launch_bounds
// (256,3) gives a ~170-reg budget: VGPR-dest MFMAs, no moves, deeper load
// pipelining (unroll 4 => 8 loads in flight). 3-node graph (yprep inits pmin).
// Math (absmax 0 since R7): bf16 hi/lo split,
//   A row m (K=16): [xh0..2, xh0..2, xl0..2, 1, 1, 0...]
//   B col n (K=16): [-2yh0..2, -2yl0..2, -2yh0..2, y2h, y2l, 0]
//   d2 = x2 + min_y (y2 - 2(xh.yh + xh.yl + xl.yh))   (xl.yl ~2^-18 dropped)

typedef short  s16x8  __attribute__((ext_vector_type(8)));
typedef float  f32x16 __attribute__((ext_vector_type(16)));

#define BATCH 4
#define NPTS  8192
#define TPB   256
#define YS    4                    // y slices per (b,dir)
#define YTILES (NPTS / 32)         // 256 y-tiles per (b,dir)
#define YTS   (YTILES / YS)        // 64 tiles per slice
#define XPB   256                  // x per block: 4 waves x 2 tiles x 32
#define NXC   (NPTS / XPB)         // 32

__device__ __forceinline__ unsigned int bft(float f) { return __float_as_uint(f) >> 16; }
__device__ __forceinline__ float bfv(unsigned int s) { return __uint_as_float(s << 16); }

// B-frags: bfrag[arr(2)][b(4)][tile(256)][half(2)][n(32)] x uint4.
// Also: pmin[gid] = +inf sentinel.
__global__ __launch_bounds__(TPB)
void yprep(const float* __restrict__ pred, const float* __restrict__ gt,
           uint4* __restrict__ bfrag, unsigned int* __restrict__ pmin) {
    const int gid = blockIdx.x * TPB + threadIdx.x;    // 0..65535
    pmin[gid] = 0xFFFFFFFFu;
    const int arr = gid >> 15;                         // 0=pred, 1=gt
    const int rem = gid & 32767;                       // b*NPTS + yi
    const int yi  = rem & (NPTS - 1);
    const float* y = (arr ? gt : pred) + (size_t)rem * 3;
    const float a0 = y[0], a1 = y[1], a2 = y[2];
    const unsigned int yh0 = bft(a0), yh1 = bft(a1), yh2 = bft(a2);
    const float l0 = a0 - bfv(yh0), l1 = a1 - bfv(yh1), l2 = a2 - bfv(yh2);
    const unsigned int nh0 = bft(-2.f * bfv(yh0));     // exact in bf16
    const unsigned int nh1 = bft(-2.f * bfv(yh1));
    const unsigned int nh2 = bft(-2.f * bfv(yh2));
    const unsigned int nl0 = bft(-2.f * l0), nl1 = bft(-2.f * l1), nl2 = bft(-2.f * l2);
    const float y2 = a0 * a0 + a1 * a1 + a2 * a2;
    const unsigned int q2h = bft(y2);
    const unsigned int q2l = bft(y2 - bfv(q2h));
    uint4 w0, w1;                                      // k-order halves
    w0.x = nh0 | (nh1 << 16);
    w0.y = nh2 | (nl0 << 16);
    w0.z = nl1 | (nl2 << 16);
    w0.w = nh0 | (nh1 << 16);
    w1.x = nh2 | (q2h << 16);
    w1.y = q2l;
    w1.z = 0u; w1.w = 0u;
    const size_t base = ((size_t)(gid >> 13) * YTILES + (yi >> 5)) * 64;  // (arr*4+b)
    bfrag[base + (yi & 31)]      = w0;
    bfrag[base + 32 + (yi & 31)] = w1;
}

__global__ __launch_bounds__(TPB, 3)   // ~170-reg budget: VGPR-dest MFMAs, deep pipeline
void nn_mfma(const float* __restrict__ pred, const float* __restrict__ gt,
             const uint4* __restrict__ bfrag, unsigned int* __restrict__ pmin) {
    const int xc = blockIdx.x, sl = blockIdx.y, bd = blockIdx.z;
    const int b = bd >> 1, dir = bd & 1;
    const float* xp = (dir ? gt : pred) + (size_t)b * NPTS * 3;
    const int yarr = dir ? 0 : 1;                      // y = dir ? pred : gt
    const uint4* bfb = bfrag + (size_t)(yarr * BATCH + b) * YTILES * 64;

    const int t = threadIdx.x;
    const int w = t >> 6, l = t & 63;
    const int m32 = l & 31, hh = l >> 5;
    const int xbase = xc * XPB + w * 64;

    // A-frags + x2 for the wave's two 32-row x-tiles.
    s16x8 af[2];
    float x2j[2];
    #pragma unroll
    for (int j = 0; j < 2; ++j) {
        const int xi = xbase + j * 32 + m32;
        const float c0 = xp[xi * 3], c1 = xp[xi * 3 + 1], c2 = xp[xi * 3 + 2];
        x2j[j] = c0 * c0 + c1 * c1 + c2 * c2;
        const unsigned int xh0 = bft(c0), xh1 = bft(c1), xh2 = bft(c2);
        const unsigned int xl0 = bft(c0 - bfv(xh0));
        const unsigned int xl1 = bft(c1 - bfv(xh1));
        const unsigned int xl2 = bft(c2 - bfv(xh2));
        s16x8 a;                                       // k = hh*8 + e
        a[0] = (short)(hh ? xl2 : xh0);
        a[1] = (short)(hh ? 0x3F80u : xh1);            // 1.0 bf16 (y2h)
        a[2] = (short)(hh ? 0x3F80u : xh2);            // 1.0 bf16 (y2l)
        a[3] = (short)(hh ? 0u : xh0);
        a[4] = (short)(hh ? 0u : xh1);
        a[5] = (short)(hh ? 0u : xh2);
        a[6] = (short)(hh ? 0u : xl0);
        a[7] = (short)(hh ? 0u : xl1);
        af[j] = a;
    }

    f32x16 zero, mn0, mn1;
    #pragma unroll
    for (int r = 0; r < 16; ++r) { zero[r] = 0.f; mn0[r] = 3.4e38f; mn1[r] = 3.4e38f; }

    // Hot loop (compiler-scheduled): per iter 2 coalesced 1KB loads (L1/L2)
    // + 4 MFMA + 32 v_min3. unroll 4 -> 8 loads in flight.
    const uint4* bp = bfb + (size_t)(sl * YTS) * 64 + l;
    #pragma unroll 4
    for (int t32 = 0; t32 < YTS; t32 += 2) {
        const s16x8 bf0 = __builtin_bit_cast(s16x8, bp[0]);
        const s16x8 bf1 = __builtin_bit_cast(s16x8, bp[64]);
        bp += 128;
        const f32x16 e00 = __builtin_amdgcn_mfma_f32_32x32x16_bf16(af[0], bf0, zero, 0, 0, 0);
        const f32x16 e01 = __builtin_amdgcn_mfma_f32_32x32x16_bf16(af[0], bf1, zero, 0, 0, 0);
        mn0 = __builtin_elementwise_min(mn0, __builtin_elementwise_min(e00, e01));
        const f32x16 e10 = __builtin_amdgcn_mfma_f32_32x32x16_bf16(af[1], bf0, zero, 0, 0, 0);
        const f32x16 e11 = __builtin_amdgcn_mfma_f32_32x32x16_bf16(af[1], bf1, zero, 0, 0, 0);
        mn1 = __builtin_elementwise_min(mn1, __builtin_elementwise_min(e10, e11));
    }

    // Butterfly min across the 32 cols (stays within each 32-lane half).
    #pragma unroll
    for (int off = 16; off; off >>= 1) {
        #pragma unroll
        for (int r = 0; r < 16; ++r) {
            mn0[r] = fminf(mn0[r], __shfl_xor(mn0[r], off, 64));
            mn1[r] = fminf(mn1[r], __shfl_xor(mn1[r], off, 64));
        }
    }

    // Lane l owns r = l&15; (l&31)>=16 -> tile1. One atomicMin per lane.
    const int r = l & 15;
    const int row = (r & 3) + 8 * (r >> 2) + 4 * hh;   // C/D row map (m74/m101)
    float v0 = mn0[0], v1 = mn1[0];
    #pragma unroll
    for (int rr = 1; rr < 16; ++rr) {
        v0 = (r == rr) ? mn0[rr] : v0;
        v1 = (r == rr) ? mn1[rr] : v1;
    }
    const float x20 = __shfl(x2j[0], row, 64);
    const float x21 = __shfl(x2j[1], row, 64);
    const bool g1 = (l & 31) >= 16;
    const float d = fmaxf((g1 ? v1 : v0) + (g1 ? x21 : x20), 0.f);
    const int xpt = xbase + (g1 ? 32 : 0) + row;
    atomicMin(&pmin[(size_t)bd * NPTS + xpt], __float_as_uint(d));
}

// One 1024-thread block: 128 threads per bd; sum + max per bd; write out[0].
__global__ __launch_bounds__(1024)
void reduce_all(const unsigned int* __restrict__ pmin, float* __restrict__ out) {
    const int t  = threadIdx.x;
    const int bd = t >> 7;
    const int l  = t & 127;
    const unsigned int* base = pmin + (size_t)bd * NPTS;
    float sum = 0.f, mx = -1.f;
    #pragma unroll
    for (int i = 0; i < NPTS / 128; ++i) {
        const float f = __uint_as_float(base[i * 128 + l]);
        sum += f;
        mx = fmaxf(mx, f);
    }
    #pragma unroll
    for (int off = 32; off; off >>= 1) {
        sum += __shfl_down(sum, off, 64);
        mx = fmaxf(mx, __shfl_down(mx, off, 64));
    }
    __shared__ float ss[16], sm[16];
    if ((t & 63) == 0) { ss[t >> 6] = sum; sm[t >> 6] = mx; }
    __syncthreads();
    if (t == 0) {
        float acc = 0.f;
        #pragma unroll
        for (int d = 0; d < 8; ++d) {
            const float S = ss[2 * d] + ss[2 * d + 1];
            const float M = fmaxf(sm[2 * d], sm[2 * d + 1]);
            acc += S * (1.f / NPTS) + ((d & 1) ? 0.f : M);   // max only for pred2gt
        }
        out[0] = acc * (1.f / BATCH);
    }
}

extern "C" void kernel_launch(void* const* d_in, const int* in_sizes, int n_in,
                              void* d_out, int out_size, void* d_ws, size_t ws_size,
                              hipStream_t stream) {
    const float* pred = (const float*)d_in[0];
    const float* gt   = (const float*)d_in[1];

    unsigned int* pmin = (unsigned int*)d_ws;                               // 256 KB
    uint4* bfrag = (uint4*)((char*)d_ws + (size_t)2 * BATCH * NPTS * 4);    // 2 MB

    yprep<<<dim3(2 * BATCH * NPTS / TPB), TPB, 0, stream>>>(pred, gt, bfrag, pmin);
    dim3 g1(NXC, YS, 2 * BATCH);   // 32 x 4 x 8 = 1024 blocks
    nn_mfma<<<g1, TPB, 0, stream>>>(pred, gt, bfrag, pmin);
    reduce_all<<<dim3(1), 1024, 0, stream>>>(pmin, (float*)d_out);
}

// Round 13
// 87.376 us; speedup vs baseline: 1.3400x; 1.1361x over previous
//
#include <hip/hip_runtime.h>

// ChamferLoss: B=4, N=M=8192, D=3, fp32.
// loss = mean_b[ mean(pred2gt) + mean(gt2pred) + max(pred2gt) ]
// R13: revert body to R8's exact config (launch_bounds(256,4), NO unroll
// pragma, compiler-scheduled global loads) -- measured best body (~26us by
// R8 budget reconstruction; R11 LDS-staging=45us, R12 unroll4=44.8us both
// regressed it). One lever on top: YS=8 (2048 blocks, 8 blocks/CU) for
// latency hiding + shorter tail. 3-node graph (yprep inits pmin).
// Math (absmax 0 since R7): bf16 hi/lo split,
//   A row m (K=16): [xh0..2, xh0..2, xl0..2, 1, 1, 0...]
//   B col n (K=16): [-2yh0..2, -2yl0..2, -2yh0..2, y2h, y2l, 0]
//   d2 = x2 + min_y (y2 - 2(xh.yh + xh.yl + xl.yh))   (xl.yl ~2^-18 dropped)

typedef short  s16x8  __attribute__((ext_vector_type(8)));
typedef float  f32x16 __attribute__((ext_vector_type(16)));

#define BATCH 4
#define NPTS  8192
#define TPB   256
#define YS    8                    // y slices per (b,dir)
#define YTILES (NPTS / 32)         // 256 y-tiles per (b,dir)
#define YTS   (YTILES / YS)        // 32 tiles per slice
#define XPB   256                  // x per block: 4 waves x 2 tiles x 32
#define NXC   (NPTS / XPB)         // 32

__device__ __forceinline__ unsigned int bft(float f) { return __float_as_uint(f) >> 16; }
__device__ __forceinline__ float bfv(unsigned int s) { return __uint_as_float(s << 16); }

// B-frags: bfrag[arr(2)][b(4)][tile(256)][half(2)][n(32)] x uint4.
// Also: pmin[gid] = +inf sentinel.
__global__ __launch_bounds__(TPB)
void yprep(const float* __restrict__ pred, const float* __restrict__ gt,
           uint4* __restrict__ bfrag, unsigned int* __restrict__ pmin) {
    const int gid = blockIdx.x * TPB + threadIdx.x;    // 0..65535
    pmin[gid] = 0xFFFFFFFFu;
    const int arr = gid >> 15;                         // 0=pred, 1=gt
    const int rem = gid & 32767;                       // b*NPTS + yi
    const int yi  = rem & (NPTS - 1);
    const float* y = (arr ? gt : pred) + (size_t)rem * 3;
    const float a0 = y[0], a1 = y[1], a2 = y[2];
    const unsigned int yh0 = bft(a0), yh1 = bft(a1), yh2 = bft(a2);
    const float l0 = a0 - bfv(yh0), l1 = a1 - bfv(yh1), l2 = a2 - bfv(yh2);
    const unsigned int nh0 = bft(-2.f * bfv(yh0));     // exact in bf16
    const unsigned int nh1 = bft(-2.f * bfv(yh1));
    const unsigned int nh2 = bft(-2.f * bfv(yh2));
    const unsigned int nl0 = bft(-2.f * l0), nl1 = bft(-2.f * l1), nl2 = bft(-2.f * l2);
    const float y2 = a0 * a0 + a1 * a1 + a2 * a2;
    const unsigned int q2h = bft(y2);
    const unsigned int q2l = bft(y2 - bfv(q2h));
    uint4 w0, w1;                                      // k-order halves
    w0.x = nh0 | (nh1 << 16);
    w0.y = nh2 | (nl0 << 16);
    w0.z = nl1 | (nl2 << 16);
    w0.w = nh0 | (nh1 << 16);
    w1.x = nh2 | (q2h << 16);
    w1.y = q2l;
    w1.z = 0u; w1.w = 0u;
    const size_t base = ((size_t)(gid >> 13) * YTILES + (yi >> 5)) * 64;  // (arr*4+b)
    bfrag[base + (yi & 31)]      = w0;
    bfrag[base + 32 + (yi & 31)] = w1;
}

__global__ __launch_bounds__(TPB, 4)   // R8's exact config (measured best body)
void nn_mfma(const float* __restrict__ pred, const float* __restrict__ gt,
             const uint4* __restrict__ bfrag, unsigned int* __restrict__ pmin) {
    const int xc = blockIdx.x, sl = blockIdx.y, bd = blockIdx.z;
    const int b = bd >> 1, dir = bd & 1;
    const float* xp = (dir ? gt : pred) + (size_t)b * NPTS * 3;
    const int yarr = dir ? 0 : 1;                      // y = dir ? pred : gt
    const uint4* bfb = bfrag + (size_t)(yarr * BATCH + b) * YTILES * 64;

    const int t = threadIdx.x;
    const int w = t >> 6, l = t & 63;
    const int m32 = l & 31, hh = l >> 5;
    const int xbase = xc * XPB + w * 64;

    // A-frags + x2 for the wave's two 32-row x-tiles.
    s16x8 af[2];
    float x2j[2];
    #pragma unroll
    for (int j = 0; j < 2; ++j) {
        const int xi = xbase + j * 32 + m32;
        const float c0 = xp[xi * 3], c1 = xp[xi * 3 + 1], c2 = xp[xi * 3 + 2];
        x2j[j] = c0 * c0 + c1 * c1 + c2 * c2;
        const unsigned int xh0 = bft(c0), xh1 = bft(c1), xh2 = bft(c2);
        const unsigned int xl0 = bft(c0 - bfv(xh0));
        const unsigned int xl1 = bft(c1 - bfv(xh1));
        const unsigned int xl2 = bft(c2 - bfv(xh2));
        s16x8 a;                                       // k = hh*8 + e
        a[0] = (short)(hh ? xl2 : xh0);
        a[1] = (short)(hh ? 0x3F80u : xh1);            // 1.0 bf16 (y2h)
        a[2] = (short)(hh ? 0x3F80u : xh2);            // 1.0 bf16 (y2l)
        a[3] = (short)(hh ? 0u : xh0);
        a[4] = (short)(hh ? 0u : xh1);
        a[5] = (short)(hh ? 0u : xh2);
        a[6] = (short)(hh ? 0u : xl0);
        a[7] = (short)(hh ? 0u : xl1);
        af[j] = a;
    }

    f32x16 zero, mn0, mn1;
    #pragma unroll
    for (int r = 0; r < 16; ++r) { zero[r] = 0.f; mn0[r] = 3.4e38f; mn1[r] = 3.4e38f; }

    // Hot loop (compiler-scheduled, no pragma): per iter 2 coalesced 1KB
    // loads (L1/L2-resident) + 4 MFMA + min3 folds.
    const uint4* bp = bfb + (size_t)(sl * YTS) * 64 + l;
    for (int t32 = 0; t32 < YTS; t32 += 2) {
        const s16x8 bf0 = __builtin_bit_cast(s16x8, bp[0]);
        const s16x8 bf1 = __builtin_bit_cast(s16x8, bp[64]);
        bp += 128;
        const f32x16 e00 = __builtin_amdgcn_mfma_f32_32x32x16_bf16(af[0], bf0, zero, 0, 0, 0);
        const f32x16 e01 = __builtin_amdgcn_mfma_f32_32x32x16_bf16(af[0], bf1, zero, 0, 0, 0);
        mn0 = __builtin_elementwise_min(mn0, __builtin_elementwise_min(e00, e01));
        const f32x16 e10 = __builtin_amdgcn_mfma_f32_32x32x16_bf16(af[1], bf0, zero, 0, 0, 0);
        const f32x16 e11 = __builtin_amdgcn_mfma_f32_32x32x16_bf16(af[1], bf1, zero, 0, 0, 0);
        mn1 = __builtin_elementwise_min(mn1, __builtin_elementwise_min(e10, e11));
    }

    // Butterfly min across the 32 cols (stays within each 32-lane half).
    #pragma unroll
    for (int off = 16; off; off >>= 1) {
        #pragma unroll
        for (int r = 0; r < 16; ++r) {
            mn0[r] = fminf(mn0[r], __shfl_xor(mn0[r], off, 64));
            mn1[r] = fminf(mn1[r], __shfl_xor(mn1[r], off, 64));
        }
    }

    // Lane l owns r = l&15; (l&31)>=16 -> tile1. One atomicMin per lane.
    const int r = l & 15;
    const int row = (r & 3) + 8 * (r >> 2) + 4 * hh;   // C/D row map (m74/m101)
    float v0 = mn0[0], v1 = mn1[0];
    #pragma unroll
    for (int rr = 1; rr < 16; ++rr) {
        v0 = (r == rr) ? mn0[rr] : v0;
        v1 = (r == rr) ? mn1[rr] : v1;
    }
    const float x20 = __shfl(x2j[0], row, 64);
    const float x21 = __shfl(x2j[1], row, 64);
    const bool g1 = (l & 31) >= 16;
    const float d = fmaxf((g1 ? v1 : v0) + (g1 ? x21 : x20), 0.f);
    const int xpt = xbase + (g1 ? 32 : 0) + row;
    atomicMin(&pmin[(size_t)bd * NPTS + xpt], __float_as_uint(d));
}

// One 1024-thread block: 128 threads per bd; sum + max per bd; write out[0].
__global__ __launch_bounds__(1024)
void reduce_all(const unsigned int* __restrict__ pmin, float* __restrict__ out) {
    const int t  = threadIdx.x;
    const int bd = t >> 7;
    const int l  = t & 127;
    const unsigned int* base = pmin + (size_t)bd * NPTS;
    float sum = 0.f, mx = -1.f;
    #pragma unroll
    for (int i = 0; i < NPTS / 128; ++i) {
        const float f = __uint_as_float(base[i * 128 + l]);
        sum += f;
        mx = fmaxf(mx, f);
    }
    #pragma unroll
    for (int off = 32; off; off >>= 1) {
        sum += __shfl_down(sum, off, 64);
        mx = fmaxf(mx, __shfl_down(mx, off, 64));
    }
    __shared__ float ss[16], sm[16];
    if ((t & 63) == 0) { ss[t >> 6] = sum; sm[t >> 6] = mx; }
    __syncthreads();
    if (t == 0) {
        float acc = 0.f;
        #pragma unroll
        for (int d = 0; d < 8; ++d) {
            const float S = ss[2 * d] + ss[2 * d + 1];
            const float M = fmaxf(sm[2 * d], sm[2 * d + 1]);
            acc += S * (1.f / NPTS) + ((d & 1) ? 0.f : M);   // max only for pred2gt
        }
        out[0] = acc * (1.f / BATCH);
    }
}

extern "C" void kernel_launch(void* const* d_in, const int* in_sizes, int n_in,
                              void* d_out, int out_size, void* d_ws, size_t ws_size,
                              hipStream_t stream) {
    const float* pred = (const float*)d_in[0];
    const float* gt   = (const float*)d_in[1];

    unsigned int* pmin = (unsigned int*)d_ws;                               // 256 KB
    uint4* bfrag = (uint4*)((char*)d_ws + (size_t)2 * BATCH * NPTS * 4);    // 2 MB

    yprep<<<dim3(2 * BATCH * NPTS / TPB), TPB, 0, stream>>>(pred, gt, bfrag, pmin);
    dim3 g1(NXC, YS, 2 * BATCH);   // 32 x 8 x 8 = 2048 blocks
    nn_mfma<<<g1, TPB, 0, stream>>>(pred, gt, bfrag, pmin);
    reduce_all<<<dim3(1), 1024, 0, stream>>>(pmin, (float*)d_out);
}